// Round 6
// baseline (243.171 us; speedup 1.0000x reference)
//
#include <hip/hip_runtime.h>
#include <hip/hip_bf16.h>

#define BATCH 8
#define CCH 1024
#define NHW 4096
#define SCALE 5.0f   // 1/TEMPERATURE
#define ROWS (BATCH * CCH)

typedef unsigned char u8;
typedef unsigned int u32;
typedef __attribute__((ext_vector_type(4))) float float4v;
typedef __attribute__((ext_vector_type(4))) u32 uint4v;

__device__ __forceinline__ void async_load16(const void* gsrc, void* ldst) {
    __builtin_amdgcn_global_load_lds(
        (__attribute__((address_space(1))) void*)gsrc,
        (__attribute__((address_space(3))) void*)ldst,
        16, 0, 0);
}

// pack 4 floats -> 4 OCP e4m3 bytes
__device__ __forceinline__ u32 pk4_fp8(float a, float b, float c, float d) {
    u32 v = __builtin_amdgcn_cvt_pk_fp8_f32(a, b, 0, false);
    v = __builtin_amdgcn_cvt_pk_fp8_f32(c, d, v, true);
    return v;
}

__device__ __forceinline__ float ssq4_fp8(u32 q) {
    float d0 = __builtin_amdgcn_cvt_f32_fp8(q, 0);
    float d1 = __builtin_amdgcn_cvt_f32_fp8(q, 1);
    float d2 = __builtin_amdgcn_cvt_f32_fp8(q, 2);
    float d3 = __builtin_amdgcn_cvt_f32_fp8(q, 3);
    return d0 * d0 + d1 * d1 + d2 * d2 + d3 * d3;
}

// One block per row: quantize x -> fp8, diag = 5*sum(q(x)^2) from QUANTIZED
// values (so the MFMA diagonal dot cancels), zero l_acc.
template <bool CONVERT>
__global__ __launch_bounds__(256) void prep_kernel(const float* __restrict__ x,
                                                   u8* __restrict__ xq,
                                                   float* __restrict__ diag,
                                                   float* __restrict__ l_acc) {
    const int row = blockIdx.x;          // 0..8191
    const int tid = threadIdx.x;
    const float* src = x + (size_t)row * NHW;
    float ssum = 0.f;
#pragma unroll
    for (int p = 0; p < 4; ++p) {
        const int idx = p * 1024 + tid * 4;
        float4 v = *(const float4*)(src + idx);
        const u32 q = pk4_fp8(v.x, v.y, v.z, v.w);
        ssum += ssq4_fp8(q);
        if (CONVERT) *(u32*)(xq + (size_t)row * NHW + idx) = q;
    }
#pragma unroll
    for (int m = 1; m < 64; m <<= 1) ssum += __shfl_xor(ssum, m);
    __shared__ float red[4];
    if ((tid & 63) == 0) red[tid >> 6] = ssum;
    __syncthreads();
    if (tid == 0) {
        diag[row] = (red[0] + red[1] + red[2] + red[3]) * SCALE;
        l_acc[row] = 0.f;
    }
}

// Symmetric Gram, fp8 e4m3, 128x64 tiles over upper triangle (bj2 >= 2*bi),
// BK=256 BYTES per K-iter -> each global_load_lds instr covers 4 rows x 256 B
// CONTIGUOUS runs (4 segments/instr instead of 16 scattered lines).
// LDS: row = 256 B = 16 chunks of 16 B; chunk (r, kc) at slot kc ^ (r&7).
//   DMA dest for instr (group g): base g*1024; lane l -> row g*4+(l>>4),
//   slot l&15, source kchunk (l&15) ^ ((g*4+(l>>4))&7)  [permutes a 256B window].
// Tiles with bj2 in {2bi, 2bi+1}: B rows subset of A rows -> alias As.
template <bool QSRC>
__global__ __launch_bounds__(256) void gram_kernel(const u8* __restrict__ Xq,
                                                   const float* __restrict__ Xf,
                                                   const float* __restrict__ diag,
                                                   float* __restrict__ l_acc,
                                                   float* __restrict__ num) {
    __shared__ __align__(16) u8 As[32768];   // 128 rows * 256 B
    __shared__ __align__(16) u8 Bs[16384];   //  64 rows * 256 B

    const int bid = blockIdx.x;
    const int b = bid & 7;           // batch -> XCD spread
    const int t = bid >> 3;          // 0..71 upper-tile index

    int bi = 0;
#pragma unroll
    for (int i = 7; i >= 1; --i) {   // off(bi) = bi*(17-bi), increasing
        if (t >= i * (17 - i)) { bi = i; break; }
    }
    const int bj2 = 2 * bi + (t - bi * (17 - bi));   // 64-col block, 0..15
    const bool aliasB = (bj2 == 2 * bi) || (bj2 == 2 * bi + 1);

    const int tid  = threadIdx.x;
    const int lane = tid & 63;
    const int w    = tid >> 6;       // wave 0..3
    const int wm   = w >> 1;         // wave row-half (64 rows)
    const int wn   = w & 1;          // wave col-half (32 cols)

    const int r4    = lane >> 4;     // 0..3 row within 4-row staging group
    const int c16   = lane & 15;     // slot within row
    const int kbase = c16 ^ r4;      // source kchunk, even groups

    const u8*    pA  = nullptr; const u8*    pB  = nullptr;
    const float* pAf = nullptr; const float* pBf = nullptr;
    if (QSRC) {
        const u8* baseX = Xq + (size_t)b * CCH * NHW;
        pA = baseX + (size_t)(bi * 128 + r4) * NHW;
        pB = baseX + (size_t)(bj2 * 64 + r4) * NHW;
    } else {
        const float* baseXf = Xf + (size_t)b * CCH * NHW;
        pAf = baseXf + (size_t)(bi * 128 + r4) * NHW;
        pBf = baseXf + (size_t)(bj2 * 64 + r4) * NHW;
    }

    float4v acc[4][2] = {};

    for (int K0 = 0; K0 < NHW; K0 += 256) {
        __syncthreads();   // previous iter's LDS reads complete
        if (QSRC) {
#pragma unroll
            for (int i = 0; i < 8; ++i) {      // A: groups g = w*8 + i
                const int g  = w * 8 + i;
                const int kc = kbase ^ ((g & 1) << 2);
                async_load16(pA + (size_t)(g * 4) * NHW + K0 + kc * 16,
                             As + (size_t)g * 1024);
            }
            if (!aliasB) {
#pragma unroll
                for (int i = 0; i < 4; ++i) {  // B: groups g = w*4 + i
                    const int g  = w * 4 + i;
                    const int kc = kbase ^ ((g & 1) << 2);
                    async_load16(pB + (size_t)(g * 4) * NHW + K0 + kc * 16,
                                 Bs + (size_t)g * 1024);
                }
            }
        } else {
#pragma unroll
            for (int i = 0; i < 8; ++i) {
                const int g  = w * 8 + i;
                const int kc = kbase ^ ((g & 1) << 2);
                const float* s = pAf + (size_t)(g * 4) * NHW + K0 + kc * 16;
                float4 f0 = *(const float4*)(s);
                float4 f1 = *(const float4*)(s + 4);
                float4 f2 = *(const float4*)(s + 8);
                float4 f3 = *(const float4*)(s + 12);
                uint4v d;
                d.x = pk4_fp8(f0.x, f0.y, f0.z, f0.w);
                d.y = pk4_fp8(f1.x, f1.y, f1.z, f1.w);
                d.z = pk4_fp8(f2.x, f2.y, f2.z, f2.w);
                d.w = pk4_fp8(f3.x, f3.y, f3.z, f3.w);
                *(uint4v*)(As + (size_t)g * 1024 + lane * 16) = d;
            }
            if (!aliasB) {
#pragma unroll
                for (int i = 0; i < 4; ++i) {
                    const int g  = w * 4 + i;
                    const int kc = kbase ^ ((g & 1) << 2);
                    const float* s = pBf + (size_t)(g * 4) * NHW + K0 + kc * 16;
                    float4 f0 = *(const float4*)(s);
                    float4 f1 = *(const float4*)(s + 4);
                    float4 f2 = *(const float4*)(s + 8);
                    float4 f3 = *(const float4*)(s + 12);
                    uint4v d;
                    d.x = pk4_fp8(f0.x, f0.y, f0.z, f0.w);
                    d.y = pk4_fp8(f1.x, f1.y, f1.z, f1.w);
                    d.z = pk4_fp8(f2.x, f2.y, f2.z, f2.w);
                    d.w = pk4_fp8(f3.x, f3.y, f3.z, f3.w);
                    *(uint4v*)(Bs + (size_t)g * 1024 + lane * 16) = d;
                }
            }
        }
        __syncthreads();   // staging visible

        const u8* Bbase = aliasB ? (As + (size_t)(bj2 - 2 * bi) * 64 * 256) : Bs;
        const int q  = lane >> 4;
        const int rl = lane & 15;
#pragma unroll
        for (int s = 0; s < 8; ++s) {          // 8 k-steps of 32 elements
            const int kc   = 2 * s + (q >> 1);             // 16B chunk 0..15
            const int boff = (int)((kc ^ (rl & 7)) * 16 + (q & 1) * 8);
            long af[4], bf[2];
#pragma unroll
            for (int mt = 0; mt < 4; ++mt)
                af[mt] = *(const long*)(As + (size_t)(wm * 64 + mt * 16 + rl) * 256 + boff);
#pragma unroll
            for (int nt = 0; nt < 2; ++nt)
                bf[nt] = *(const long*)(Bbase + (size_t)(wn * 32 + nt * 16 + rl) * 256 + boff);
#pragma unroll
            for (int mt = 0; mt < 4; ++mt)
#pragma unroll
                for (int nt = 0; nt < 2; ++nt)
                    acc[mt][nt] = __builtin_amdgcn_mfma_f32_16x16x32_fp8_fp8(af[mt], bf[nt], acc[mt][nt], 0, 0, 0);
        }
    }

    // ---- Epilogue ----
    const int q  = lane >> 4;    // row-quad 0..3
    const int cl = lane & 15;    // col within 16
    const int rowbase = bi * 128 + wm * 64;
    const int colbase = bj2 * 64 + wn * 32;
    const float* dgb = diag + b * CCH;
    float* lb = l_acc + b * CCH;

    // Row sums (upper-inclusive) + diagonal numerator
#pragma unroll
    for (int mt = 0; mt < 4; ++mt) {
#pragma unroll
        for (int reg = 0; reg < 4; ++reg) {
            const int gr = rowbase + mt * 16 + q * 4 + reg;
            const float dg = dgb[gr];
            float s = 0.f;
#pragma unroll
            for (int nt = 0; nt < 2; ++nt) {
                const int gc = colbase + nt * 16 + cl;
                const float e = __expf(acc[mt][nt][reg] * SCALE - dg);
                if (gr <= gc) s += e;
                if (gr == gc) num[b * CCH + gr] = e;
            }
            s += __shfl_xor(s, 1);
            s += __shfl_xor(s, 2);
            s += __shfl_xor(s, 4);
            s += __shfl_xor(s, 8);
            if (cl == 0) atomicAdd(lb + gr, s);
        }
    }

    // Column sums (strictly-upper -> transposed contribution)
#pragma unroll
    for (int nt = 0; nt < 2; ++nt) {
        const int gc = colbase + nt * 16 + cl;
        const float dgc = dgb[gc];
        float s = 0.f;
#pragma unroll
        for (int mt = 0; mt < 4; ++mt) {
#pragma unroll
            for (int reg = 0; reg < 4; ++reg) {
                const int gr = rowbase + mt * 16 + q * 4 + reg;
                if (gr < gc) s += __expf(acc[mt][nt][reg] * SCALE - dgc);
            }
        }
        s += __shfl_xor(s, 16);
        s += __shfl_xor(s, 32);
        if (lane < 16) atomicAdd(lb + gc, s);
    }
}

__global__ __launch_bounds__(1024) void finalize_kernel(const float* __restrict__ l_acc,
                                                        const float* __restrict__ num,
                                                        float* __restrict__ out) {
    const int tid = threadIdx.x;
    float s = 0.f;
    for (int r = tid; r < ROWS; r += 1024) {
        const float d = num[r] / l_acc[r];
        s += -__logf(d + 1e-10f);
    }
#pragma unroll
    for (int m = 1; m < 64; m <<= 1) s += __shfl_xor(s, m);
    __shared__ float red[16];
    if ((tid & 63) == 0) red[tid >> 6] = s;
    __syncthreads();
    if (tid == 0) {
        float tot = 0.f;
#pragma unroll
        for (int i = 0; i < 16; ++i) tot += red[i];
        out[0] = tot * (1.0f / (float)ROWS);
    }
}

extern "C" void kernel_launch(void* const* d_in, const int* in_sizes, int n_in,
                              void* d_out, int out_size, void* d_ws, size_t ws_size,
                              hipStream_t stream) {
    const float* x = (const float*)d_in[0];
    float* out = (float*)d_out;

    const size_t xq_bytes   = (size_t)BATCH * CCH * NHW;      // 33554432 (fp8)
    const size_t stat_bytes = (size_t)ROWS * 4;               // 32768
    const bool fast = ws_size >= xq_bytes + 3 * stat_bytes;

    const int ntiles = 72;  // 128x64 upper-triangle tiles per batch

    if (fast) {
        u8*    xq    = (u8*)d_ws;
        float* diag  = (float*)((char*)d_ws + xq_bytes);
        float* l_acc = diag + ROWS;
        float* num   = l_acc + ROWS;
        prep_kernel<true><<<ROWS, 256, 0, stream>>>(x, xq, diag, l_acc);
        gram_kernel<true><<<BATCH * ntiles, 256, 0, stream>>>(xq, nullptr, diag, l_acc, num);
        finalize_kernel<<<1, 1024, 0, stream>>>(l_acc, num, out);
    } else {
        float* diag  = (float*)d_ws;
        float* l_acc = diag + ROWS;
        float* num   = l_acc + ROWS;
        prep_kernel<false><<<ROWS, 256, 0, stream>>>(x, nullptr, diag, l_acc);
        gram_kernel<false><<<BATCH * ntiles, 256, 0, stream>>>(nullptr, x, diag, l_acc, num);
        finalize_kernel<<<1, 1024, 0, stream>>>(l_acc, num, out);
    }
}

// Round 7
// 241.000 us; speedup vs baseline: 1.0090x; 1.0090x over previous
//
#include <hip/hip_runtime.h>
#include <hip/hip_bf16.h>

#define BATCH 8
#define CCH 1024
#define NHW 4096
#define SCALE 5.0f   // 1/TEMPERATURE
#define ROWS (BATCH * CCH)

typedef unsigned char u8;
typedef unsigned int u32;
typedef __attribute__((ext_vector_type(4))) float float4v;
typedef __attribute__((ext_vector_type(4))) u32 uint4v;

__device__ __forceinline__ void async_load16(const void* gsrc, void* ldst) {
    __builtin_amdgcn_global_load_lds(
        (__attribute__((address_space(1))) void*)gsrc,
        (__attribute__((address_space(3))) void*)ldst,
        16, 0, 0);
}

// pack 4 floats -> 4 OCP e4m3 bytes
__device__ __forceinline__ u32 pk4_fp8(float a, float b, float c, float d) {
    u32 v = __builtin_amdgcn_cvt_pk_fp8_f32(a, b, 0, false);
    v = __builtin_amdgcn_cvt_pk_fp8_f32(c, d, v, true);
    return v;
}

__device__ __forceinline__ float ssq4_fp8(u32 q) {
    float d0 = __builtin_amdgcn_cvt_f32_fp8(q, 0);
    float d1 = __builtin_amdgcn_cvt_f32_fp8(q, 1);
    float d2 = __builtin_amdgcn_cvt_f32_fp8(q, 2);
    float d3 = __builtin_amdgcn_cvt_f32_fp8(q, 3);
    return d0 * d0 + d1 * d1 + d2 * d2 + d3 * d3;
}

// One block per row: quantize x -> fp8, diag = 5*sum(q(x)^2) from QUANTIZED
// values (so the MFMA diagonal dot cancels), zero l_acc.
template <bool CONVERT>
__global__ __launch_bounds__(256) void prep_kernel(const float* __restrict__ x,
                                                   u8* __restrict__ xq,
                                                   float* __restrict__ diag,
                                                   float* __restrict__ l_acc) {
    const int row = blockIdx.x;          // 0..8191
    const int tid = threadIdx.x;
    const float* src = x + (size_t)row * NHW;
    float ssum = 0.f;
#pragma unroll
    for (int p = 0; p < 4; ++p) {
        const int idx = p * 1024 + tid * 4;
        float4 v = *(const float4*)(src + idx);
        const u32 q = pk4_fp8(v.x, v.y, v.z, v.w);
        ssum += ssq4_fp8(q);
        if (CONVERT) *(u32*)(xq + (size_t)row * NHW + idx) = q;
    }
#pragma unroll
    for (int m = 1; m < 64; m <<= 1) ssum += __shfl_xor(ssum, m);
    __shared__ float red[4];
    if ((tid & 63) == 0) red[tid >> 6] = ssum;
    __syncthreads();
    if (tid == 0) {
        diag[row] = (red[0] + red[1] + red[2] + red[3]) * SCALE;
        l_acc[row] = 0.f;
    }
}

// Symmetric Gram, fp8 e4m3, 128x64 tiles over upper triangle (bj2 >= 2*bi),
// BK=128, DOUBLE-BUFFERED with prefetch-before-compute: DMAs for iter k+1 are
// issued before the MFMA work of iter k, so the vmcnt(0) drain at the
// end-of-iter barrier happens after ~600 cyc of compute instead of immediately.
// LDS: row = 128 B = 8 chunks of 16 B; chunk (r, kc) at slot kc ^ (r&7)
// -> DMA coalesced, frag reads ~2-way bank-aliased (free).
// Tiles with bj2 in {2bi, 2bi+1}: B rows subset of A rows -> alias As.
template <bool QSRC>
__global__ __launch_bounds__(256) void gram_kernel(const u8* __restrict__ Xq,
                                                   const float* __restrict__ Xf,
                                                   const float* __restrict__ diag,
                                                   float* __restrict__ l_acc,
                                                   float* __restrict__ num) {
    __shared__ __align__(16) u8 As[2][16384];   // 128 rows * 128 B, x2
    __shared__ __align__(16) u8 Bs[2][8192];    //  64 rows * 128 B, x2

    const int bid = blockIdx.x;
    const int b = bid & 7;           // batch -> XCD spread
    const int t = bid >> 3;          // 0..71 upper-tile index

    int bi = 0;
#pragma unroll
    for (int i = 7; i >= 1; --i) {   // off(bi) = bi*(17-bi), increasing
        if (t >= i * (17 - i)) { bi = i; break; }
    }
    const int bj2 = 2 * bi + (t - bi * (17 - bi));   // 64-col block, 0..15
    const bool aliasB = (bj2 == 2 * bi) || (bj2 == 2 * bi + 1);

    const int tid  = threadIdx.x;
    const int lane = tid & 63;
    const int w    = tid >> 6;       // wave 0..3
    const int wm   = w >> 1;         // wave row-half (64 rows)
    const int wn   = w & 1;          // wave col-half (32 cols)

    // Staging: instr covers 8 rows x 8 slots. lane l -> row l>>3, slot l&7,
    // source kchunk = (l&7) ^ (l>>3).
    const int st_r  = lane >> 3;               // 0..7
    const int st_kc = (lane & 7) ^ st_r;       // source 16B-chunk

    const u8*    pA  = nullptr; const u8*    pB  = nullptr;
    const float* pAf = nullptr; const float* pBf = nullptr;
    if (QSRC) {
        const u8* baseX = Xq + (size_t)b * CCH * NHW;
        pA = baseX + (size_t)(bi * 128 + w * 32 + st_r) * NHW + st_kc * 16;
        pB = baseX + (size_t)(bj2 * 64 + w * 16 + st_r) * NHW + st_kc * 16;
    } else {
        const float* baseXf = Xf + (size_t)b * CCH * NHW;
        pAf = baseXf + (size_t)(bi * 128 + w * 32 + st_r) * NHW + st_kc * 16;
        pBf = baseXf + (size_t)(bj2 * 64 + w * 16 + st_r) * NHW + st_kc * 16;
    }

    float4v acc[4][2] = {};

    // ---- stage(buf, K0) ----
    auto stage = [&](int buf, int K0) {
        if (QSRC) {
#pragma unroll
            for (int t8 = 0; t8 < 4; ++t8)     // A: 32 rows per wave
                async_load16(pA + (size_t)(t8 * 8) * NHW + K0,
                             As[buf] + (size_t)(w * 32 + t8 * 8) * 128);
            if (!aliasB) {
#pragma unroll
                for (int t8 = 0; t8 < 2; ++t8) // B: 16 rows per wave
                    async_load16(pB + (size_t)(t8 * 8) * NHW + K0,
                                 Bs[buf] + (size_t)(w * 16 + t8 * 8) * 128);
            }
        } else {
#pragma unroll
            for (int t8 = 0; t8 < 4; ++t8) {
                const float* s = pAf + (size_t)(t8 * 8) * NHW + K0;
                float4 f0 = *(const float4*)(s);
                float4 f1 = *(const float4*)(s + 4);
                float4 f2 = *(const float4*)(s + 8);
                float4 f3 = *(const float4*)(s + 12);
                uint4v d;
                d.x = pk4_fp8(f0.x, f0.y, f0.z, f0.w);
                d.y = pk4_fp8(f1.x, f1.y, f1.z, f1.w);
                d.z = pk4_fp8(f2.x, f2.y, f2.z, f2.w);
                d.w = pk4_fp8(f3.x, f3.y, f3.z, f3.w);
                *(uint4v*)(As[buf] + (size_t)(w * 32 + t8 * 8 + st_r) * 128 + (lane & 7) * 16) = d;
            }
            if (!aliasB) {
#pragma unroll
                for (int t8 = 0; t8 < 2; ++t8) {
                    const float* s = pBf + (size_t)(t8 * 8) * NHW + K0;
                    float4 f0 = *(const float4*)(s);
                    float4 f1 = *(const float4*)(s + 4);
                    float4 f2 = *(const float4*)(s + 8);
                    float4 f3 = *(const float4*)(s + 12);
                    uint4v d;
                    d.x = pk4_fp8(f0.x, f0.y, f0.z, f0.w);
                    d.y = pk4_fp8(f1.x, f1.y, f1.z, f1.w);
                    d.z = pk4_fp8(f2.x, f2.y, f2.z, f2.w);
                    d.w = pk4_fp8(f3.x, f3.y, f3.z, f3.w);
                    *(uint4v*)(Bs[buf] + (size_t)(w * 16 + t8 * 8 + st_r) * 128 + (lane & 7) * 16) = d;
                }
            }
        }
    };

    stage(0, 0);
    __syncthreads();                 // publish buffer 0 (full drain, once)

    for (int i = 0; i < NHW / 128; ++i) {
        const int cur = i & 1;
        const int K0n = (i + 1) * 128;
        if (K0n < NHW) stage(cur ^ 1, K0n);   // prefetch BEFORE compute

        const u8* Ab = As[cur];
        const u8* Bb = aliasB ? (Ab + (size_t)(bj2 - 2 * bi) * 64 * 128) : Bs[cur];
        const int q  = lane >> 4;
        const int rl = lane & 15;
#pragma unroll
        for (int s = 0; s < 4; ++s) {          // 4 k-steps of 32 elements
            const int cbase = 2 * s + (q >> 1);            // 16B chunk 0..7
            const int boff  = (int)((cbase ^ (rl & 7)) * 16 + (q & 1) * 8);
            long af[4], bf[2];
#pragma unroll
            for (int mt = 0; mt < 4; ++mt)
                af[mt] = *(const long*)(Ab + (size_t)(wm * 64 + mt * 16 + rl) * 128 + boff);
#pragma unroll
            for (int nt = 0; nt < 2; ++nt)
                bf[nt] = *(const long*)(Bb + (size_t)(wn * 32 + nt * 16 + rl) * 128 + boff);
#pragma unroll
            for (int mt = 0; mt < 4; ++mt)
#pragma unroll
                for (int nt = 0; nt < 2; ++nt)
                    acc[mt][nt] = __builtin_amdgcn_mfma_f32_16x16x32_fp8_fp8(af[mt], bf[nt], acc[mt][nt], 0, 0, 0);
        }
        __syncthreads();   // publish prefetched buffer (drain hidden behind compute)
    }

    // ---- Epilogue ----
    const int q  = lane >> 4;    // row-quad 0..3
    const int cl = lane & 15;    // col within 16
    const int rowbase = bi * 128 + wm * 64;
    const int colbase = bj2 * 64 + wn * 32;
    const float* dgb = diag + b * CCH;
    float* lb = l_acc + b * CCH;

    // Row sums (upper-inclusive) + diagonal numerator
#pragma unroll
    for (int mt = 0; mt < 4; ++mt) {
#pragma unroll
        for (int reg = 0; reg < 4; ++reg) {
            const int gr = rowbase + mt * 16 + q * 4 + reg;
            const float dg = dgb[gr];
            float s = 0.f;
#pragma unroll
            for (int nt = 0; nt < 2; ++nt) {
                const int gc = colbase + nt * 16 + cl;
                const float e = __expf(acc[mt][nt][reg] * SCALE - dg);
                if (gr <= gc) s += e;
                if (gr == gc) num[b * CCH + gr] = e;
            }
            s += __shfl_xor(s, 1);
            s += __shfl_xor(s, 2);
            s += __shfl_xor(s, 4);
            s += __shfl_xor(s, 8);
            if (cl == 0) atomicAdd(lb + gr, s);
        }
    }

    // Column sums (strictly-upper -> transposed contribution)
#pragma unroll
    for (int nt = 0; nt < 2; ++nt) {
        const int gc = colbase + nt * 16 + cl;
        const float dgc = dgb[gc];
        float s = 0.f;
#pragma unroll
        for (int mt = 0; mt < 4; ++mt) {
#pragma unroll
            for (int reg = 0; reg < 4; ++reg) {
                const int gr = rowbase + mt * 16 + q * 4 + reg;
                if (gr < gc) s += __expf(acc[mt][nt][reg] * SCALE - dgc);
            }
        }
        s += __shfl_xor(s, 16);
        s += __shfl_xor(s, 32);
        if (lane < 16) atomicAdd(lb + gc, s);
    }
}

__global__ __launch_bounds__(1024) void finalize_kernel(const float* __restrict__ l_acc,
                                                        const float* __restrict__ num,
                                                        float* __restrict__ out) {
    const int tid = threadIdx.x;
    float s = 0.f;
    for (int r = tid; r < ROWS; r += 1024) {
        const float d = num[r] / l_acc[r];
        s += -__logf(d + 1e-10f);
    }
#pragma unroll
    for (int m = 1; m < 64; m <<= 1) s += __shfl_xor(s, m);
    __shared__ float red[16];
    if ((tid & 63) == 0) red[tid >> 6] = s;
    __syncthreads();
    if (tid == 0) {
        float tot = 0.f;
#pragma unroll
        for (int i = 0; i < 16; ++i) tot += red[i];
        out[0] = tot * (1.0f / (float)ROWS);
    }
}

extern "C" void kernel_launch(void* const* d_in, const int* in_sizes, int n_in,
                              void* d_out, int out_size, void* d_ws, size_t ws_size,
                              hipStream_t stream) {
    const float* x = (const float*)d_in[0];
    float* out = (float*)d_out;

    const size_t xq_bytes   = (size_t)BATCH * CCH * NHW;      // 33554432 (fp8)
    const size_t stat_bytes = (size_t)ROWS * 4;               // 32768
    const bool fast = ws_size >= xq_bytes + 3 * stat_bytes;

    const int ntiles = 72;  // 128x64 upper-triangle tiles per batch

    if (fast) {
        u8*    xq    = (u8*)d_ws;
        float* diag  = (float*)((char*)d_ws + xq_bytes);
        float* l_acc = diag + ROWS;
        float* num   = l_acc + ROWS;
        prep_kernel<true><<<ROWS, 256, 0, stream>>>(x, xq, diag, l_acc);
        gram_kernel<true><<<BATCH * ntiles, 256, 0, stream>>>(xq, nullptr, diag, l_acc, num);
        finalize_kernel<<<1, 1024, 0, stream>>>(l_acc, num, out);
    } else {
        float* diag  = (float*)d_ws;
        float* l_acc = diag + ROWS;
        float* num   = l_acc + ROWS;
        prep_kernel<false><<<ROWS, 256, 0, stream>>>(x, nullptr, diag, l_acc);
        gram_kernel<false><<<BATCH * ntiles, 256, 0, stream>>>(nullptr, x, diag, l_acc, num);
        finalize_kernel<<<1, 1024, 0, stream>>>(l_acc, num, out);
    }
}